// Round 10
// baseline (512.426 us; speedup 1.0000x reference)
//
#include <hip/hip_runtime.h>
#include <hip/hip_bf16.h>
#include <stdint.h>

// ConvIntrinsic: fused  out[k,o,t] = relu( Σ_f sw[t,f]·ms[k,f]
//                + Σ_{x,y,f} W3[o,t,x,y,f]·interp0[k,x,y,f] + bias[t] )
// => GEMM (K=100000 × 1312) @ (1312 × 768), o=8 column duplicates o=0.
//
// R9: BK=64 — two chunks per barrier window. Cross-round invariant: per-block
// per-chunk period ≈ 4370 cy regardless of work/traffic/barrier-flavor =>
// fixed per-window serialization (loaded gather latency exposed once per
// barrier interval, 2 waves/SIMD can't cover it). Halve the windows: 41 -> 21.
// Per interval: issue 2 chunks' gathers (top) -> 48 MFMA -> commit both
// (bottom) -> 1 barrier. Gather slack ~2x, B slack ~2x. A-build, bf16 ms
// table, barrier form, epilogue: R8-verbatim.

typedef __attribute__((ext_vector_type(8))) short short8;
typedef __attribute__((ext_vector_type(4))) float floatx4;
typedef __attribute__((ext_vector_type(2))) float fx2;

#define KPTS 100000
#define OUT_STRIDE 864   // 9*96
#define BM 64
#define THREADS 512
#define BP_SHORTS 1007616   // 41*48*64*8

// Workgroup barrier without vmcnt drain (R7 form).
#define BARRIER() do {                              \
    __builtin_amdgcn_sched_barrier(0);              \
    asm volatile("s_waitcnt lgkmcnt(0)");           \
    __builtin_amdgcn_s_barrier();                   \
  } while (0)

__device__ __forceinline__ short f2bf(float x) {
  union { float f; uint32_t u; } c; c.f = x;
  uint32_t u = c.u;
  u += 0x7FFFu + ((u >> 16) & 1u);   // round-to-nearest-even
  return (short)(u >> 16);
}
__device__ __forceinline__ float bf2f(short s) {
  union { uint32_t u; float f; } c;
  c.u = ((uint32_t)(uint16_t)s) << 16;
  return c.f;
}

// ---------------- prep: ms -> bf16 table --------------------------------
__global__ void prep_ms(const float* __restrict__ ms, short* __restrict__ msb) {
  const int i = (blockIdx.x * 256 + threadIdx.x) * 8;
  if (i < KPTS * 32) {
    floatx4 a = *(const floatx4*)(ms + i);
    floatx4 b = *(const floatx4*)(ms + i + 4);
    short8 s;
#pragma unroll
    for (int j = 0; j < 4; ++j) { s[j] = f2bf(a[j]); s[4 + j] = f2bf(b[j]); }
    *reinterpret_cast<short8*>(msb + i) = s;
  }
}

// ---------------- prep: pack B in MFMA fragment layout --------------------
// Bp[ch][ntile][lane][j] = B[c = ch*32 + (lane>>4)*8 + j][n = ntile*16 + (lane&15)]
__global__ void prep_B(const float* __restrict__ kern,
                       const float* __restrict__ tw,
                       const float* __restrict__ sw,
                       short* __restrict__ Bp) {
  const int ntile = blockIdx.x;   // 0..47
  const int ch    = blockIdx.y;   // 0..40
  const int lane  = threadIdx.x;  // 0..63
  const int n = ntile * 16 + (lane & 15);
  const int o = n / 96;
  const int t = n - o * 96;
  const int fb = (lane >> 4) * 8;

  short8 v;
  if (ch < 40) {
    float kcol[40];
#pragma unroll
    for (int ra = 0; ra < 40; ++ra) kcol[ra] = kern[ra * 40 + ch];
#pragma unroll
    for (int j = 0; j < 8; ++j) {
      const int f = fb + j;
      float acc = 0.f;
      for (int r = 0; r < 5; ++r) {
#pragma unroll
        for (int a = 0; a < 8; ++a) {
          acc += kcol[r * 8 + a] * tw[((t * 5 + r) * 8 + ((a + o) & 7)) * 32 + f];
        }
      }
      v[j] = f2bf(acc);
    }
  } else {
#pragma unroll
    for (int j = 0; j < 8; ++j) v[j] = f2bf(sw[t * 32 + fb + j]);
  }
  *reinterpret_cast<short8*>(Bp + ((size_t)(ch * 48 + ntile) * 64 + lane) * 8) = v;
}

// ---------------- main fused GEMM ----------------------------------------
__global__ __launch_bounds__(THREADS, 1) void conv_main(
    const short* __restrict__ msb,
    const float* __restrict__ bary,
    const float* __restrict__ bias,
    const short* __restrict__ Bp,
    float* __restrict__ out) {
  __shared__ short Atile[2][BM][68];   // 64 k-cols (2 chunks) + 4 pad shorts

  const int kbase = blockIdx.x * BM;
  const int tid = threadIdx.x;
  const int lane = tid & 63;
  const int wn = tid >> 6;             // 0..7  (wave n-group: cols wn*96)
  const int l15 = lane & 15;
  const int kh = lane >> 4;            // 0..3

  // A-build role: 4 threads per row, 8 bf16 f-columns each; 256 builders.
  const bool builder = tid < 256;
  const int arow = tid >> 2;           // 0..63 for builders
  const int af0 = (tid & 3) * 8;       // 0,8,16,24
  const int krow = kbase + (arow & 63);
  const bool rowok = builder && (krow < KPTS);
  const float* __restrict__ brow = bary + (size_t)(rowok ? krow : 0) * 240;
  const short* __restrict__ mrowb = msb + (size_t)(rowok ? krow : 0) * 32 + af0;

  // bary triples, parity sets (E = even intervals, O = odd), a = even chunk,
  // b = odd chunk of the interval being issued
  fx2 bEa0, bEa1, bEa2, bEb0, bEb1, bEb2;
  fx2 bOa0, bOa1, bOa2, bOb0, bOb1, bOb2;
  // gather regs: issued top-of-interval, committed bottom-of-interval
  short8 G0, G1, G2, G3, G4, G5;
  float W0, W1, W2, W3, W4, W5;

  auto ldbary = [&](int c, fx2& p0, fx2& p1, fx2& p2) {
    if (rowok) {
      const fx2* bp = (const fx2*)(brow + c * 6);
      p0 = __builtin_nontemporal_load(bp);
      p1 = __builtin_nontemporal_load(bp + 1);
      p2 = __builtin_nontemporal_load(bp + 2);
    } else {
      p0 = (fx2)0.f; p1 = (fx2)0.f; p2 = (fx2)0.f;
    }
  };
  auto issueG = [&](int c, const fx2& p0, const fx2& p1, const fx2& p2,
                    short8& A, short8& B, short8& C,
                    float& V0, float& V1, float& V2) {
    if (c == 40) {   // center chunk: A[k][1280+f] = ms[k][f] (pass-through)
      A = *(const short8*)(mrowb);
      B = A; C = A;
      V0 = rowok ? 1.f : 0.f; V1 = 0.f; V2 = 0.f;
    } else {
      A = *(const short8*)(msb + ((size_t)(int)p0.x) * 32 + af0);
      B = *(const short8*)(msb + ((size_t)(int)p1.x) * 32 + af0);
      C = *(const short8*)(msb + ((size_t)(int)p2.x) * 32 + af0);
      V0 = p0.y; V1 = p1.y; V2 = p2.y;
    }
  };
  auto commitG = [&](const short8& A, const short8& B, const short8& C,
                     float V0, float V1, float V2, int buf, int half) {
    short8 s;
#pragma unroll
    for (int j = 0; j < 8; ++j)
      s[j] = f2bf(V0 * bf2f(A[j]) + V1 * bf2f(B[j]) + V2 * bf2f(C[j]));
    *reinterpret_cast<short8*>(&Atile[buf][arow][half * 32 + af0]) = s;
  };

  short8 bfA[6], bfB[6];
  auto loadB = [&](int c, short8* dst) {
    const short* bp = Bp + ((size_t)(c * 48 + wn * 6) * 64 + lane) * 8;
#pragma unroll
    for (int j = 0; j < 6; ++j)
      dst[j] = *reinterpret_cast<const short8*>(bp + (size_t)j * 512);
  };

  floatx4 acc[4][6];
#pragma unroll
  for (int mi = 0; mi < 4; ++mi)
#pragma unroll
    for (int nj = 0; nj < 6; ++nj) acc[mi][nj] = (floatx4)0.f;

  // ---- prologue: build chunks 0,1 into buf0; preload bary 2..5; B(0) ----
  if (builder) {
    fx2 t0, t1, t2;
    ldbary(0, t0, t1, t2);
    issueG(0, t0, t1, t2, G0, G1, G2, W0, W1, W2);
    ldbary(1, t0, t1, t2);
    issueG(1, t0, t1, t2, G3, G4, G5, W3, W4, W5);
    ldbary(2, bEa0, bEa1, bEa2);
    ldbary(3, bEb0, bEb1, bEb2);
    ldbary(4, bOa0, bOa1, bOa2);
    ldbary(5, bOb0, bOb1, bOb2);
    commitG(G0, G1, G2, W0, W1, W2, 0, 0);
    commitG(G3, G4, G5, W3, W4, W5, 0, 1);
  }
  loadB(0, bfA);
  BARRIER();

  // Interval i: MFMA chunks 2i (bfA), 2i+1 (bfB) from buf (i&1);
  // issue gathers for 2i+2, 2i+3 (top), commit them (bottom) -> buf^1;
  // refill this parity's bary with chunks 2i+6, 2i+7; loadB(2i+1) top,
  // loadB(2i+2) mid. One barrier per interval.
#define INTERVAL(i, QA0, QA1, QA2, QB0, QB1, QB2)                               \
  {                                                                             \
    const int cur = (i) & 1;                                                    \
    loadB(2 * (i) + 1, bfB);                                                    \
    if (builder) {                                                              \
      if (2 * (i) + 2 <= 40)                                                    \
        issueG(2 * (i) + 2, QA0, QA1, QA2, G0, G1, G2, W0, W1, W2);             \
      if (2 * (i) + 3 <= 39)                                                    \
        issueG(2 * (i) + 3, QB0, QB1, QB2, G3, G4, G5, W3, W4, W5);             \
      if (2 * (i) + 6 <= 39) ldbary(2 * (i) + 6, QA0, QA1, QA2);                \
      if (2 * (i) + 7 <= 39) ldbary(2 * (i) + 7, QB0, QB1, QB2);                \
    }                                                                           \
    short8 af[4];                                                               \
    _Pragma("unroll")                                                           \
    for (int mi = 0; mi < 4; ++mi)                                              \
      af[mi] = *reinterpret_cast<const short8*>(&Atile[cur][mi * 16 + l15][kh * 8]); \
    _Pragma("unroll")                                                           \
    for (int nj = 0; nj < 6; ++nj)                                              \
      _Pragma("unroll")                                                         \
      for (int mi = 0; mi < 4; ++mi)                                            \
        acc[mi][nj] = __builtin_amdgcn_mfma_f32_16x16x32_bf16(af[mi], bfA[nj],  \
                                                              acc[mi][nj], 0, 0, 0); \
    if (2 * (i) + 2 <= 40) loadB(2 * (i) + 2, bfA);                             \
    _Pragma("unroll")                                                           \
    for (int mi = 0; mi < 4; ++mi)                                              \
      af[mi] = *reinterpret_cast<const short8*>(&Atile[cur][mi * 16 + l15][32 + kh * 8]); \
    _Pragma("unroll")                                                           \
    for (int nj = 0; nj < 6; ++nj)                                              \
      _Pragma("unroll")                                                         \
      for (int mi = 0; mi < 4; ++mi)                                            \
        acc[mi][nj] = __builtin_amdgcn_mfma_f32_16x16x32_bf16(af[mi], bfB[nj],  \
                                                              acc[mi][nj], 0, 0, 0); \
    if (builder) {                                                              \
      if (2 * (i) + 2 <= 40)                                                    \
        commitG(G0, G1, G2, W0, W1, W2, cur ^ 1, 0);                            \
      if (2 * (i) + 3 <= 39)                                                    \
        commitG(G3, G4, G5, W3, W4, W5, cur ^ 1, 1);                            \
    }                                                                           \
    BARRIER();                                                                  \
  }

  for (int ii = 0; ii < 20; ii += 2) {
    INTERVAL(ii,     bEa0, bEa1, bEa2, bEb0, bEb1, bEb2)
    INTERVAL(ii + 1, bOa0, bOa1, bOa2, bOb0, bOb1, bOb2)
  }
#undef INTERVAL

  // tail: chunk 40 (center) sits in buf0 half 0; B = bfA (loaded at i=19)
  {
    short8 af[4];
#pragma unroll
    for (int mi = 0; mi < 4; ++mi)
      af[mi] = *reinterpret_cast<const short8*>(&Atile[0][mi * 16 + l15][kh * 8]);
#pragma unroll
    for (int nj = 0; nj < 6; ++nj)
#pragma unroll
      for (int mi = 0; mi < 4; ++mi)
        acc[mi][nj] = __builtin_amdgcn_mfma_f32_16x16x32_bf16(af[mi], bfA[nj],
                                                              acc[mi][nj], 0, 0, 0);
  }

  // epilogue: bias + relu; out[k,o,t] = out[k*864 + n]; o=8 duplicates o=0
#pragma unroll
  for (int mi = 0; mi < 4; ++mi) {
    const int rb = kbase + mi * 16 + kh * 4;
#pragma unroll
    for (int nj = 0; nj < 6; ++nj) {
      const int n = wn * 96 + nj * 16 + l15;
      const float bsv = bias[nj * 16 + l15];
      const bool dup = (wn == 0);
#pragma unroll
      for (int i = 0; i < 4; ++i) {
        const int r = rb + i;
        if (r < KPTS) {
          float vv = fmaxf(acc[mi][nj][i] + bsv, 0.f);
          out[(size_t)r * OUT_STRIDE + n] = vv;
          if (dup) out[(size_t)r * OUT_STRIDE + 768 + n] = vv;
        }
      }
    }
  }
}

extern "C" void kernel_launch(void* const* d_in, const int* in_sizes, int n_in,
                              void* d_out, int out_size, void* d_ws, size_t ws_size,
                              hipStream_t stream) {
  const float* ms   = (const float*)d_in[0];  // (K,32)
  const float* bary = (const float*)d_in[1];  // (K,5,8,3,2)
  const float* kern = (const float*)d_in[2];  // (5,8,5,8)
  const float* tw   = (const float*)d_in[3];  // (96,5,8,32)
  const float* sw   = (const float*)d_in[4];  // (96,1,32)
  const float* bias = (const float*)d_in[5];  // (96,)
  float* out = (float*)d_out;
  short* Bp  = (short*)d_ws;                  // 2.02 MB
  short* msb = (short*)d_ws + BP_SHORTS;      // bf16 ms table, 6.4 MB

  hipLaunchKernelGGL(prep_B, dim3(48, 41), dim3(64), 0, stream, kern, tw, sw, Bp);
  hipLaunchKernelGGL(prep_ms, dim3((KPTS * 32 / 8 + 255) / 256), dim3(256), 0, stream,
                     ms, msb);
  hipLaunchKernelGGL(conv_main, dim3(1563), dim3(THREADS), 0, stream,
                     msb, bary, bias, Bp, out);
}